// Round 1
// baseline (145.412 us; speedup 1.0000x reference)
//
#include <hip/hip_runtime.h>
#include <hip/hip_bf16.h>

typedef __attribute__((ext_vector_type(8))) __bf16 bf16x8;
typedef __attribute__((ext_vector_type(4))) float f32x4;
typedef unsigned short u16;

#define NB 8192
#define ND 128
#define NCHUNK 16
#define NEGINF (-__builtin_inff())
#define POSINF (__builtin_inff())

__device__ inline u16 f2b(float f){
  __hip_bfloat16 h = __float2bfloat16(f);
  return *reinterpret_cast<u16*>(&h);
}

// ---- prep: fp32 -> bf16, colp[row] = (sq, p=1/(1-sq), sq*p, lab_bits) ------
// also zeroes the final-reduction cells so fin_k's atomic finish is
// graph-replay-safe (stream order: prep -> gram -> fin every iteration).
extern "C" __global__ __launch_bounds__(256)
void prep_k(const float* __restrict__ x, const int* __restrict__ lab,
            u16* __restrict__ xb, float4* __restrict__ colp,
            float* __restrict__ gred, unsigned int* __restrict__ done)
{
  if (blockIdx.x == 0 && threadIdx.x == 0){
    gred[0] = 0.0f; gred[1] = 0.0f; *done = 0u;
  }
  const int tid = blockIdx.x * 256 + threadIdx.x;
  const int row = tid >> 5;           // 32 threads per row
  const int sub = tid & 31;
  const float4 v = reinterpret_cast<const float4*>(x)[row * 32 + sub];
  float s = v.x*v.x + v.y*v.y + v.z*v.z + v.w*v.w;
  #pragma unroll
  for (int m = 1; m < 32; m <<= 1) s += __shfl_xor(s, m, 32);
  ushort4 o;
  o.x = f2b(v.x); o.y = f2b(v.y); o.z = f2b(v.z); o.w = f2b(v.w);
  reinterpret_cast<ushort4*>(xb)[row * 32 + sub] = o;
  if (sub == 0){
    const float p = 1.0f / (1.0f - s);
    colp[row] = make_float4(s, p, s * p, __int_as_float(lab[row]));
  }
}

// ---- main: bf16 MFMA gram tiles + streaming row max/min --------------------
// grid (64, 16): x = 128-row tile, y = 512-col chunk. 4 waves, each 32 rows.
// K-loop: 8 half-tiles of 64 cols, double-buffered in 2x16KB LDS.
// Stage for half-tile s+1 is issued BEFORE computing half-tile s, so the
// vmcnt(0) drain inside the ending __syncthreads lands after ~600cy of
// compute -> stage latency hidden (T3-minimum 2-phase pattern).
extern "C" __global__ __launch_bounds__(256, 4)
void gram_k(const u16* __restrict__ xb, const float4* __restrict__ colp,
            float* __restrict__ ppos, float* __restrict__ pneg)
{
  __shared__ u16 Bt[2][64 * 128];   // 2 x 16 KB double buffer, 256B/col,
                                    // 16B chunks XOR-swizzled by col&15
  const int wid  = threadIdx.x >> 6;
  const int lane = threadIdx.x & 63;
  const int m16  = lane & 15;
  const int quad = lane >> 4;
  const int R0  = blockIdx.x * 128;
  const int C0  = blockIdx.y * 512;
  const int WR0 = R0 + wid * 32;

  // A fragments in registers: A[m=lane&15][k=quad*8+j]
  bf16x8 afrag[2][4];
  #pragma unroll
  for (int mt = 0; mt < 2; ++mt){
    const u16* arow = xb + (WR0 + mt*16 + m16) * ND;
    #pragma unroll
    for (int ks = 0; ks < 4; ++ks)
      afrag[mt][ks] = *reinterpret_cast<const bf16x8*>(arow + ks*32 + quad*8);
  }

  // per-row (C/D row = quad*4 + r) params
  float sqi[8]; int labi[8];
  #pragma unroll
  for (int mt = 0; mt < 2; ++mt)
    #pragma unroll
    for (int r = 0; r < 4; ++r){
      const float4 cp = colp[WR0 + mt*16 + quad*4 + r];
      sqi[mt*4+r]  = cp.x;
      labi[mt*4+r] = __float_as_int(cp.w);
    }

  float vpos[8], vneg[8];
  #pragma unroll
  for (int i = 0; i < 8; ++i){ vpos[i] = NEGINF; vneg[i] = POSINF; }

  // stage 64 B-rows (16 KB) into buffer b. LDS[col][slot] holds global
  // chunk (slot ^ (col&15)); dest is lane-linear as global_load_lds needs.
  auto stage = [&](int s, int b){
    const int CT0 = C0 + s * 64;
    #pragma unroll
    for (int c = 0; c < 4; ++c){
      const int cc   = wid * 4 + c;        // 16 calls x 1KB = 16KB
      const int brow = cc * 4 + quad;      // stage-local col 0..63
      const int src  = m16 ^ (brow & 15);
      const u16* gsrc = xb + (CT0 + brow) * ND + src * 8;
      __builtin_amdgcn_global_load_lds(
          (__attribute__((address_space(1))) void*)gsrc,
          (__attribute__((address_space(3))) void*)(&Bt[b][cc * 512]), 16, 0, 0);
    }
  };

  auto compute = [&](int s, int b){
    const int CT0 = C0 + s * 64;
    // column params prefetched at phase top: issued before the MFMA block,
    // consumed in the epilogue -> L2 latency hidden under MFMA.
    float4 cp4[4];
    #pragma unroll
    for (int nt = 0; nt < 4; ++nt)
      cp4[nt] = colp[CT0 + nt*16 + m16];

    f32x4 acc[2][4];
    #pragma unroll
    for (int mt = 0; mt < 2; ++mt)
      #pragma unroll
      for (int nt = 0; nt < 4; ++nt){
        f32x4 z = {0.f, 0.f, 0.f, 0.f};
        acc[mt][nt] = z;
      }

    #pragma unroll
    for (int ks = 0; ks < 4; ++ks){
      const int t = ks * 4 + quad;                 // 16B chunk index in col
      // per-lane base; nt and buffer terms are compile-time -> fold into
      // the ds_read 16-bit offset immediate (b*16384 + nt*4096 bytes)
      const u16* bb = &Bt[b][0] + m16 * 128 + ((t ^ m16) * 8);
      #pragma unroll
      for (int nt = 0; nt < 4; ++nt){
        const bf16x8 bfrag = *reinterpret_cast<const bf16x8*>(bb + nt * 2048);
        acc[0][nt] = __builtin_amdgcn_mfma_f32_16x16x32_bf16(afrag[0][ks], bfrag, acc[0][nt], 0, 0, 0);
        acc[1][nt] = __builtin_amdgcn_mfma_f32_16x16x32_bf16(afrag[1][ks], bfrag, acc[1][nt], 0, 0, 0);
      }
    }

    // epilogue: u = (sq_i + sq_j - 2g) * p_j  (no interior clamp; fin clamps)
    #pragma unroll
    for (int nt = 0; nt < 4; ++nt){
      const float pj   = cp4[nt].y;
      const float spj  = cp4[nt].z;
      const int   labj = __float_as_int(cp4[nt].w);
      const float n2pj = -2.0f * pj;
      #pragma unroll
      for (int mt = 0; mt < 2; ++mt){
        const bool tilediag = (WR0 + mt*16) == (CT0 + nt*16);
        if (!tilediag){
          #pragma unroll
          for (int r = 0; r < 4; ++r){
            const int idx = mt*4 + r;
            const float u = fmaf(n2pj, acc[mt][nt][r], fmaf(sqi[idx], pj, spj));
            const bool sm = (labi[idx] == labj);
            vpos[idx] = fmaxf(vpos[idx], sm ? u : NEGINF);
            vneg[idx] = fminf(vneg[idx], sm ? POSINF : u);
          }
        } else {
          #pragma unroll
          for (int r = 0; r < 4; ++r){
            const int idx = mt*4 + r;
            const float u = fmaf(n2pj, acc[mt][nt][r], fmaf(sqi[idx], pj, spj));
            const bool sm = (labi[idx] == labj);
            const bool dg = (m16 == quad*4 + r);
            vpos[idx] = fmaxf(vpos[idx], (sm && !dg) ? u : NEGINF);
            vneg[idx] = fminf(vneg[idx], sm ? POSINF : u);
          }
        }
      }
    }
  };

  // pipelined main loop: one barrier per half-tile, stage overlapped.
  stage(0, 0);
  __syncthreads();                       // drains vmcnt(0): tile 0 ready
  #pragma unroll
  for (int s = 0; s < 8; ++s){
    const int b = s & 1;
    if (s < 7) stage(s + 1, b ^ 1);      // issue next half-tile first
    compute(s, b);
    if (s < 7) __syncthreads();          // vmcnt(0)+barrier: next tile ready,
  }                                      // buf b free for overwrite next iter

  // row i lives in the 16 lanes of one quad-group: reduce across them
  #pragma unroll
  for (int i = 0; i < 8; ++i){
    #pragma unroll
    for (int m = 1; m < 16; m <<= 1){
      vpos[i] = fmaxf(vpos[i], __shfl_xor(vpos[i], m, 16));
      vneg[i] = fminf(vneg[i], __shfl_xor(vneg[i], m, 16));
    }
  }
  if (m16 == 0){
    #pragma unroll
    for (int i = 0; i < 8; ++i){
      const int row = WR0 + (i >> 2)*16 + quad*4 + (i & 3);
      ppos[blockIdx.y * NB + row] = vpos[i];
      pneg[blockIdx.y * NB + row] = vneg[i];
    }
  }
}

// ---- finalize (fused): 64 blocks x 128 rows -> atomic finish ---------------
extern "C" __global__ __launch_bounds__(128)
void fin_k(const float* __restrict__ ppos, const float* __restrict__ pneg,
           const float4* __restrict__ colp, float* __restrict__ gred,
           unsigned int* __restrict__ done, float* __restrict__ out)
{
  const int row = blockIdx.x * 128 + threadIdx.x;
  float up = NEGINF, un = POSINF;
  #pragma unroll
  for (int c = 0; c < NCHUNK; ++c){
    up = fmaxf(up, ppos[c * NB + row]);
    un = fminf(un, pneg[c * NB + row]);
  }
  const bool hp = (up > NEGINF);
  const bool hn = (un < POSINF);
  const float pi = colp[row].y;
  float dp = 0.0f, dn = 0.0f;
  // arccosh(1+t) = log1p(t + sqrt(t*(t+2))), t clamped at 1e-7 (matches ref)
  if (hp){ float t = fmaxf(2.0f * up * pi, 1e-7f); dp = log1pf(t + sqrtf(t * (t + 2.0f))); }
  if (hn){ float t = fmaxf(2.0f * un * pi, 1e-7f); dn = log1pf(t + sqrtf(t * (t + 2.0f))); }
  float lsum = (hp && hn) ? fmaxf(dp - dn + 0.5f, 0.0f) : 0.0f;
  float lcnt = (hp && hn) ? 1.0f : 0.0f;
  #pragma unroll
  for (int m = 1; m < 64; m <<= 1){
    lsum += __shfl_xor(lsum, m, 64);
    lcnt += __shfl_xor(lcnt, m, 64);
  }
  __shared__ float2 s_p[2];
  if ((threadIdx.x & 63) == 0) s_p[threadIdx.x >> 6] = make_float2(lsum, lcnt);
  __syncthreads();
  if (threadIdx.x == 0){
    const float bs = s_p[0].x + s_p[1].x;
    const float bc = s_p[0].y + s_p[1].y;
    atomicAdd(&gred[0], bs);
    atomicAdd(&gred[1], bc);
    __threadfence();
    const unsigned int prev = atomicAdd(done, 1u);
    if (prev == 63u){                      // last block: all adds visible
      __threadfence();
      const float s = atomicAdd(&gred[0], 0.0f);   // read via atomic (L2)
      const float c = atomicAdd(&gred[1], 0.0f);
      out[0] = (c > 0.0f) ? (s / c) : 0.0f;
    }
  }
}

extern "C" void kernel_launch(void* const* d_in, const int* in_sizes, int n_in,
                              void* d_out, int out_size, void* d_ws, size_t ws_size,
                              hipStream_t stream)
{
  const float* x  = (const float*)d_in[0];
  const int* lab  = (const int*)d_in[1];
  char* ws = (char*)d_ws;
  u16*    xb   = (u16*)ws;                                        // 2 MB
  float4* colp = (float4*)(ws + (size_t)2*1024*1024);             // 128 KB
  float*  ppos = (float*)(ws + (size_t)2*1024*1024 + 128*1024);   // 512 KB
  float*  pneg = (float*)(ws + (size_t)2*1024*1024 + 128*1024 + 512*1024); // 512 KB
  float*  gred = (float*)(ws + (size_t)2*1024*1024 + 128*1024 + 1024*1024); // 8 B
  unsigned int* done = (unsigned int*)(ws + (size_t)2*1024*1024 + 128*1024
                                          + 1024*1024 + 64);      // 4 B

  hipLaunchKernelGGL(prep_k, dim3(1024), dim3(256), 0, stream, x, lab, xb, colp,
                     gred, done);
  hipLaunchKernelGGL(gram_k, dim3(64, NCHUNK), dim3(256), 0, stream,
                     xb, colp, ppos, pneg);
  hipLaunchKernelGGL(fin_k, dim3(64), dim3(128), 0, stream, ppos, pneg, colp,
                     gred, done, (float*)d_out);
}

// Round 2
// 127.490 us; speedup vs baseline: 1.1406x; 1.1406x over previous
//
#include <hip/hip_runtime.h>
#include <hip/hip_bf16.h>

typedef __attribute__((ext_vector_type(8))) __bf16 bf16x8;
typedef __attribute__((ext_vector_type(4))) float f32x4;
typedef unsigned short u16;

#define NB 8192
#define ND 128
#define NCHUNK 16
#define NEGINF (-__builtin_inff())
#define POSINF (__builtin_inff())

__device__ inline u16 f2b(float f){
  __hip_bfloat16 h = __float2bfloat16(f);
  return *reinterpret_cast<u16*>(&h);
}

// ---- prep: fp32 -> bf16, colp[row] = (sq, p=1/(1-sq), sq*p, lab_bits) ------
// also zeroes the final-reduction cells so fin_k's atomic finish is
// graph-replay-safe (stream order: prep -> gram -> fin every iteration).
extern "C" __global__ __launch_bounds__(256)
void prep_k(const float* __restrict__ x, const int* __restrict__ lab,
            u16* __restrict__ xb, float4* __restrict__ colp,
            float* __restrict__ gred, unsigned int* __restrict__ done)
{
  if (blockIdx.x == 0 && threadIdx.x == 0){
    gred[0] = 0.0f; gred[1] = 0.0f; *done = 0u;
  }
  const int tid = blockIdx.x * 256 + threadIdx.x;
  const int row = tid >> 5;           // 32 threads per row
  const int sub = tid & 31;
  const float4 v = reinterpret_cast<const float4*>(x)[row * 32 + sub];
  float s = v.x*v.x + v.y*v.y + v.z*v.z + v.w*v.w;
  #pragma unroll
  for (int m = 1; m < 32; m <<= 1) s += __shfl_xor(s, m, 32);
  ushort4 o;
  o.x = f2b(v.x); o.y = f2b(v.y); o.z = f2b(v.z); o.w = f2b(v.w);
  reinterpret_cast<ushort4*>(xb)[row * 32 + sub] = o;
  if (sub == 0){
    const float p = 1.0f / (1.0f - s);
    colp[row] = make_float4(s, p, s * p, __int_as_float(lab[row]));
  }
}

// ---- main: bf16 MFMA gram tiles + streaming row max/min --------------------
// grid (64, 16): x = 128-row tile, y = 512-col chunk. 4 waves, each 32 rows.
// K-loop: 8 half-tiles of 64 cols, double-buffered in 2x16KB LDS, stage for
// s+1 issued before compute(s) so the vmcnt(0) drain in the trailing
// __syncthreads lands after ~1200cy of compute (T3-minimum 2-phase).
// REGISTER DISCIPLINE (round-1 lesson): nothing new live across the MFMA
// block — colp loads stay inside the epilogue, per-nt. Holding cp4[4]
// across the MFMAs pushed past the 128-reg unified budget at (256,4) and
// spilled: 91 MB scratch writes, gram_k 84us.
extern "C" __global__ __launch_bounds__(256, 4)
void gram_k(const u16* __restrict__ xb, const float4* __restrict__ colp,
            float* __restrict__ ppos, float* __restrict__ pneg)
{
  __shared__ u16 Bt[2][64 * 128];   // 2 x 16 KB double buffer, 256B/col,
                                    // 16B chunks XOR-swizzled by col&15
  const int wid  = threadIdx.x >> 6;
  const int lane = threadIdx.x & 63;
  const int m16  = lane & 15;
  const int quad = lane >> 4;
  const int R0  = blockIdx.x * 128;
  const int C0  = blockIdx.y * 512;
  const int WR0 = R0 + wid * 32;

  // A fragments in registers: A[m=lane&15][k=quad*8+j]
  bf16x8 afrag[2][4];
  #pragma unroll
  for (int mt = 0; mt < 2; ++mt){
    const u16* arow = xb + (WR0 + mt*16 + m16) * ND;
    #pragma unroll
    for (int ks = 0; ks < 4; ++ks)
      afrag[mt][ks] = *reinterpret_cast<const bf16x8*>(arow + ks*32 + quad*8);
  }

  // per-row (C/D row = quad*4 + r) params
  float sqi[8]; int labi[8];
  #pragma unroll
  for (int mt = 0; mt < 2; ++mt)
    #pragma unroll
    for (int r = 0; r < 4; ++r){
      const float4 cp = colp[WR0 + mt*16 + quad*4 + r];
      sqi[mt*4+r]  = cp.x;
      labi[mt*4+r] = __float_as_int(cp.w);
    }

  float vpos[8], vneg[8];
  #pragma unroll
  for (int i = 0; i < 8; ++i){ vpos[i] = NEGINF; vneg[i] = POSINF; }

  // stage 64 B-rows (16 KB) into buffer b. LDS[col][slot] holds global
  // chunk (slot ^ (col&15)); dest is lane-linear as global_load_lds needs.
  auto stage = [&](int s, int b){
    const int CT0 = C0 + s * 64;
    #pragma unroll
    for (int c = 0; c < 4; ++c){
      const int cc   = wid * 4 + c;        // 16 calls x 1KB = 16KB
      const int brow = cc * 4 + quad;      // stage-local col 0..63
      const int src  = m16 ^ (brow & 15);
      const u16* gsrc = xb + (CT0 + brow) * ND + src * 8;
      __builtin_amdgcn_global_load_lds(
          (__attribute__((address_space(1))) void*)gsrc,
          (__attribute__((address_space(3))) void*)(&Bt[b][cc * 512]), 16, 0, 0);
    }
  };

  auto compute = [&](int s, int b){
    const int CT0 = C0 + s * 64;
    f32x4 acc[2][4];
    #pragma unroll
    for (int mt = 0; mt < 2; ++mt)
      #pragma unroll
      for (int nt = 0; nt < 4; ++nt){
        f32x4 z = {0.f, 0.f, 0.f, 0.f};
        acc[mt][nt] = z;
      }

    #pragma unroll
    for (int ks = 0; ks < 4; ++ks){
      const int t = ks * 4 + quad;                 // 16B chunk index in col
      // per-lane base; nt and buffer terms are compile-time -> fold into
      // the ds_read 16-bit offset immediate
      const u16* bb = &Bt[b][0] + m16 * 128 + ((t ^ m16) * 8);
      #pragma unroll
      for (int nt = 0; nt < 4; ++nt){
        const bf16x8 bfrag = *reinterpret_cast<const bf16x8*>(bb + nt * 2048);
        acc[0][nt] = __builtin_amdgcn_mfma_f32_16x16x32_bf16(afrag[0][ks], bfrag, acc[0][nt], 0, 0, 0);
        acc[1][nt] = __builtin_amdgcn_mfma_f32_16x16x32_bf16(afrag[1][ks], bfrag, acc[1][nt], 0, 0, 0);
      }
    }

    // epilogue: u = (sq_i + sq_j - 2g) * p_j  (no interior clamp; fin clamps)
    // colp loaded HERE, per-nt, transient — not held across the MFMA block.
    #pragma unroll
    for (int nt = 0; nt < 4; ++nt){
      const float4 cp = colp[CT0 + nt*16 + m16];
      const float pj   = cp.y;
      const float spj  = cp.z;
      const int   labj = __float_as_int(cp.w);
      const float n2pj = -2.0f * pj;
      #pragma unroll
      for (int mt = 0; mt < 2; ++mt){
        const bool tilediag = (WR0 + mt*16) == (CT0 + nt*16);
        if (!tilediag){
          #pragma unroll
          for (int r = 0; r < 4; ++r){
            const int idx = mt*4 + r;
            const float u = fmaf(n2pj, acc[mt][nt][r], fmaf(sqi[idx], pj, spj));
            const bool sm = (labi[idx] == labj);
            vpos[idx] = fmaxf(vpos[idx], sm ? u : NEGINF);
            vneg[idx] = fminf(vneg[idx], sm ? POSINF : u);
          }
        } else {
          #pragma unroll
          for (int r = 0; r < 4; ++r){
            const int idx = mt*4 + r;
            const float u = fmaf(n2pj, acc[mt][nt][r], fmaf(sqi[idx], pj, spj));
            const bool sm = (labi[idx] == labj);
            const bool dg = (m16 == quad*4 + r);
            vpos[idx] = fmaxf(vpos[idx], (sm && !dg) ? u : NEGINF);
            vneg[idx] = fminf(vneg[idx], sm ? POSINF : u);
          }
        }
      }
    }
  };

  // pipelined main loop: one barrier per half-tile, stage overlapped.
  stage(0, 0);
  __syncthreads();                       // drains vmcnt(0): tile 0 ready
  #pragma unroll
  for (int s = 0; s < 8; ++s){
    const int b = s & 1;
    if (s < 7) stage(s + 1, b ^ 1);      // issue next half-tile first
    compute(s, b);
    if (s < 7) __syncthreads();          // vmcnt(0)+barrier: next tile ready,
  }                                      // buf b free for overwrite next iter

  // row i lives in the 16 lanes of one quad-group: reduce across them
  #pragma unroll
  for (int i = 0; i < 8; ++i){
    #pragma unroll
    for (int m = 1; m < 16; m <<= 1){
      vpos[i] = fmaxf(vpos[i], __shfl_xor(vpos[i], m, 16));
      vneg[i] = fminf(vneg[i], __shfl_xor(vneg[i], m, 16));
    }
  }
  if (m16 == 0){
    #pragma unroll
    for (int i = 0; i < 8; ++i){
      const int row = WR0 + (i >> 2)*16 + quad*4 + (i & 3);
      ppos[blockIdx.y * NB + row] = vpos[i];
      pneg[blockIdx.y * NB + row] = vneg[i];
    }
  }
}

// ---- finalize (fused): 64 blocks x 128 rows -> atomic finish ---------------
extern "C" __global__ __launch_bounds__(128)
void fin_k(const float* __restrict__ ppos, const float* __restrict__ pneg,
           const float4* __restrict__ colp, float* __restrict__ gred,
           unsigned int* __restrict__ done, float* __restrict__ out)
{
  const int row = blockIdx.x * 128 + threadIdx.x;
  float up = NEGINF, un = POSINF;
  #pragma unroll
  for (int c = 0; c < NCHUNK; ++c){
    up = fmaxf(up, ppos[c * NB + row]);
    un = fminf(un, pneg[c * NB + row]);
  }
  const bool hp = (up > NEGINF);
  const bool hn = (un < POSINF);
  const float pi = colp[row].y;
  float dp = 0.0f, dn = 0.0f;
  // arccosh(1+t) = log1p(t + sqrt(t*(t+2))), t clamped at 1e-7 (matches ref)
  if (hp){ float t = fmaxf(2.0f * up * pi, 1e-7f); dp = log1pf(t + sqrtf(t * (t + 2.0f))); }
  if (hn){ float t = fmaxf(2.0f * un * pi, 1e-7f); dn = log1pf(t + sqrtf(t * (t + 2.0f))); }
  float lsum = (hp && hn) ? fmaxf(dp - dn + 0.5f, 0.0f) : 0.0f;
  float lcnt = (hp && hn) ? 1.0f : 0.0f;
  #pragma unroll
  for (int m = 1; m < 64; m <<= 1){
    lsum += __shfl_xor(lsum, m, 64);
    lcnt += __shfl_xor(lcnt, m, 64);
  }
  __shared__ float2 s_p[2];
  if ((threadIdx.x & 63) == 0) s_p[threadIdx.x >> 6] = make_float2(lsum, lcnt);
  __syncthreads();
  if (threadIdx.x == 0){
    const float bs = s_p[0].x + s_p[1].x;
    const float bc = s_p[0].y + s_p[1].y;
    atomicAdd(&gred[0], bs);
    atomicAdd(&gred[1], bc);
    __threadfence();
    const unsigned int prev = atomicAdd(done, 1u);
    if (prev == 63u){                      // last block: all adds visible
      __threadfence();
      const float s = atomicAdd(&gred[0], 0.0f);   // read via atomic (L2)
      const float c = atomicAdd(&gred[1], 0.0f);
      out[0] = (c > 0.0f) ? (s / c) : 0.0f;
    }
  }
}

extern "C" void kernel_launch(void* const* d_in, const int* in_sizes, int n_in,
                              void* d_out, int out_size, void* d_ws, size_t ws_size,
                              hipStream_t stream)
{
  const float* x  = (const float*)d_in[0];
  const int* lab  = (const int*)d_in[1];
  char* ws = (char*)d_ws;
  u16*    xb   = (u16*)ws;                                        // 2 MB
  float4* colp = (float4*)(ws + (size_t)2*1024*1024);             // 128 KB
  float*  ppos = (float*)(ws + (size_t)2*1024*1024 + 128*1024);   // 512 KB
  float*  pneg = (float*)(ws + (size_t)2*1024*1024 + 128*1024 + 512*1024); // 512 KB
  float*  gred = (float*)(ws + (size_t)2*1024*1024 + 128*1024 + 1024*1024); // 8 B
  unsigned int* done = (unsigned int*)(ws + (size_t)2*1024*1024 + 128*1024
                                          + 1024*1024 + 64);      // 4 B

  hipLaunchKernelGGL(prep_k, dim3(1024), dim3(256), 0, stream, x, lab, xb, colp,
                     gred, done);
  hipLaunchKernelGGL(gram_k, dim3(64, NCHUNK), dim3(256), 0, stream,
                     xb, colp, ppos, pneg);
  hipLaunchKernelGGL(fin_k, dim3(64), dim3(128), 0, stream, ppos, pneg, colp,
                     gred, done, (float*)d_out);
}

// Round 3
// 103.787 us; speedup vs baseline: 1.4011x; 1.2284x over previous
//
#include <hip/hip_runtime.h>
#include <hip/hip_bf16.h>

typedef __attribute__((ext_vector_type(8))) __bf16 bf16x8;
typedef __attribute__((ext_vector_type(4))) float f32x4;
typedef unsigned short u16;

#define NB 8192
#define ND 128
#define NCHUNK 16
#define NEGINF (-__builtin_inff())
#define POSINF (__builtin_inff())

__device__ inline u16 f2b(float f){
  __hip_bfloat16 h = __float2bfloat16(f);
  return *reinterpret_cast<u16*>(&h);
}

// ---- prep: fp32 -> bf16, colp[row] = (sq, p=1/(1-sq), sq*p, lab_bits) ------
// also zeroes the final-reduction cells so fin_k's atomic finish is
// graph-replay-safe (stream order: prep -> gram -> fin every iteration).
extern "C" __global__ __launch_bounds__(256)
void prep_k(const float* __restrict__ x, const int* __restrict__ lab,
            u16* __restrict__ xb, float4* __restrict__ colp,
            float* __restrict__ gred, unsigned int* __restrict__ done)
{
  if (blockIdx.x == 0 && threadIdx.x == 0){
    gred[0] = 0.0f; gred[1] = 0.0f; *done = 0u;
  }
  const int tid = blockIdx.x * 256 + threadIdx.x;
  const int row = tid >> 5;           // 32 threads per row
  const int sub = tid & 31;
  const float4 v = reinterpret_cast<const float4*>(x)[row * 32 + sub];
  float s = v.x*v.x + v.y*v.y + v.z*v.z + v.w*v.w;
  #pragma unroll
  for (int m = 1; m < 32; m <<= 1) s += __shfl_xor(s, m, 32);
  ushort4 o;
  o.x = f2b(v.x); o.y = f2b(v.y); o.z = f2b(v.z); o.w = f2b(v.w);
  reinterpret_cast<ushort4*>(xb)[row * 32 + sub] = o;
  if (sub == 0){
    const float p = 1.0f / (1.0f - s);
    colp[row] = make_float4(s, p, s * p, __int_as_float(lab[row]));
  }
}

// ---- main: bf16 MFMA gram tiles + streaming row max/min --------------------
// grid (64, 16): x = 128-row tile, y = 512-col chunk. 4 waves, each 32 rows.
// K-loop: 8 half-tiles of 64 cols, double-buffered in 2x16KB LDS; stage for
// half-tile s+1 issued before compute(s) (T3-minimum 2-phase).
// PRESSURE DISCIPLINE (rounds 1-2 lesson): demand ~130 regs; launch_bounds
// (256,4) capped the budget at 128 -> 20-90 MB scratch traffic every round.
// (256,3) gives ~170 regs/wave: no spill, and achieved occupancy was only
// ~2.5-3 blocks/CU anyway. The pipeline loop is ROLLED (unroll 1, explicit
// even/odd bodies) so stage addresses stay incremental, not 8x-hoisted.
extern "C" __global__ __launch_bounds__(256, 3)
void gram_k(const u16* __restrict__ xb, const float4* __restrict__ colp,
            float* __restrict__ ppos, float* __restrict__ pneg)
{
  __shared__ u16 Bt[2][64 * 128];   // 2 x 16 KB double buffer, 256B/col,
                                    // 16B chunks XOR-swizzled by col&15
  const int wid  = threadIdx.x >> 6;
  const int lane = threadIdx.x & 63;
  const int m16  = lane & 15;
  const int quad = lane >> 4;
  const int R0  = blockIdx.x * 128;
  const int C0  = blockIdx.y * 512;
  const int WR0 = R0 + wid * 32;

  // A fragments in registers: A[m=lane&15][k=quad*8+j]
  bf16x8 afrag[2][4];
  #pragma unroll
  for (int mt = 0; mt < 2; ++mt){
    const u16* arow = xb + (WR0 + mt*16 + m16) * ND;
    #pragma unroll
    for (int ks = 0; ks < 4; ++ks)
      afrag[mt][ks] = *reinterpret_cast<const bf16x8*>(arow + ks*32 + quad*8);
  }

  // per-row (C/D row = quad*4 + r) params
  float sqi[8]; int labi[8];
  #pragma unroll
  for (int mt = 0; mt < 2; ++mt)
    #pragma unroll
    for (int r = 0; r < 4; ++r){
      const float4 cp = colp[WR0 + mt*16 + quad*4 + r];
      sqi[mt*4+r]  = cp.x;
      labi[mt*4+r] = __float_as_int(cp.w);
    }

  float vpos[8], vneg[8];
  #pragma unroll
  for (int i = 0; i < 8; ++i){ vpos[i] = NEGINF; vneg[i] = POSINF; }

  // stage 64 B-rows (16 KB) into buffer b. LDS[col][slot] holds global
  // chunk (slot ^ (col&15)); dest is lane-linear as global_load_lds needs.
  auto stage = [&](int s, int b){
    const int CT0 = C0 + s * 64;
    #pragma unroll
    for (int c = 0; c < 4; ++c){
      const int cc   = wid * 4 + c;        // 16 calls x 1KB = 16KB
      const int brow = cc * 4 + quad;      // stage-local col 0..63
      const int src  = m16 ^ (brow & 15);
      const u16* gsrc = xb + (CT0 + brow) * ND + src * 8;
      __builtin_amdgcn_global_load_lds(
          (__attribute__((address_space(1))) void*)gsrc,
          (__attribute__((address_space(3))) void*)(&Bt[b][cc * 512]), 16, 0, 0);
    }
  };

  auto compute = [&](int s, int b){
    const int CT0 = C0 + s * 64;
    f32x4 acc[2][4];
    #pragma unroll
    for (int mt = 0; mt < 2; ++mt)
      #pragma unroll
      for (int nt = 0; nt < 4; ++nt){
        f32x4 z = {0.f, 0.f, 0.f, 0.f};
        acc[mt][nt] = z;
      }

    #pragma unroll
    for (int ks = 0; ks < 4; ++ks){
      const int t = ks * 4 + quad;                 // 16B chunk index in col
      // per-lane base; nt and buffer terms are compile-time -> fold into
      // the ds_read 16-bit offset immediate
      const u16* bb = &Bt[b][0] + m16 * 128 + ((t ^ m16) * 8);
      #pragma unroll
      for (int nt = 0; nt < 4; ++nt){
        const bf16x8 bfrag = *reinterpret_cast<const bf16x8*>(bb + nt * 2048);
        acc[0][nt] = __builtin_amdgcn_mfma_f32_16x16x32_bf16(afrag[0][ks], bfrag, acc[0][nt], 0, 0, 0);
        acc[1][nt] = __builtin_amdgcn_mfma_f32_16x16x32_bf16(afrag[1][ks], bfrag, acc[1][nt], 0, 0, 0);
      }
    }

    // epilogue: u = (sq_i + sq_j - 2g) * p_j  (no interior clamp; fin clamps)
    // colp loaded HERE, per-nt, transient — not held across the MFMA block.
    #pragma unroll
    for (int nt = 0; nt < 4; ++nt){
      const float4 cp = colp[CT0 + nt*16 + m16];
      const float pj   = cp.y;
      const float spj  = cp.z;
      const int   labj = __float_as_int(cp.w);
      const float n2pj = -2.0f * pj;
      #pragma unroll
      for (int mt = 0; mt < 2; ++mt){
        const bool tilediag = (WR0 + mt*16) == (CT0 + nt*16);
        if (!tilediag){
          #pragma unroll
          for (int r = 0; r < 4; ++r){
            const int idx = mt*4 + r;
            const float u = fmaf(n2pj, acc[mt][nt][r], fmaf(sqi[idx], pj, spj));
            const bool sm = (labi[idx] == labj);
            vpos[idx] = fmaxf(vpos[idx], sm ? u : NEGINF);
            vneg[idx] = fminf(vneg[idx], sm ? POSINF : u);
          }
        } else {
          #pragma unroll
          for (int r = 0; r < 4; ++r){
            const int idx = mt*4 + r;
            const float u = fmaf(n2pj, acc[mt][nt][r], fmaf(sqi[idx], pj, spj));
            const bool sm = (labi[idx] == labj);
            const bool dg = (m16 == quad*4 + r);
            vpos[idx] = fmaxf(vpos[idx], (sm && !dg) ? u : NEGINF);
            vneg[idx] = fminf(vneg[idx], sm ? POSINF : u);
          }
        }
      }
    }
  };

  // pipelined main loop, ROLLED: each iteration handles half-tiles
  // {2ss, 2ss+1} in buffers {0, 1}. Buffer indices are literals; s is
  // runtime so addresses stay incremental (no 8x hoisted address sets).
  stage(0, 0);
  __syncthreads();                       // drains vmcnt(0): tile 0 ready
  #pragma unroll 1
  for (int ss = 0; ss < 4; ++ss){
    const int s0 = ss * 2;
    stage(s0 + 1, 1);                    // overwrite buf1 (all done reading:
                                         // barrier at end of prev iter)
    compute(s0, 0);
    __syncthreads();                     // buf1 staged; buf0 consumed
    if (ss < 3) stage(s0 + 2, 0);
    compute(s0 + 1, 1);
    if (ss < 3) __syncthreads();         // buf0 staged; buf1 consumed
  }

  // row i lives in the 16 lanes of one quad-group: reduce across them
  #pragma unroll
  for (int i = 0; i < 8; ++i){
    #pragma unroll
    for (int m = 1; m < 16; m <<= 1){
      vpos[i] = fmaxf(vpos[i], __shfl_xor(vpos[i], m, 16));
      vneg[i] = fminf(vneg[i], __shfl_xor(vneg[i], m, 16));
    }
  }
  if (m16 == 0){
    #pragma unroll
    for (int i = 0; i < 8; ++i){
      const int row = WR0 + (i >> 2)*16 + quad*4 + (i & 3);
      ppos[blockIdx.y * NB + row] = vpos[i];
      pneg[blockIdx.y * NB + row] = vneg[i];
    }
  }
}

// ---- finalize (fused): 64 blocks x 128 rows -> atomic finish ---------------
extern "C" __global__ __launch_bounds__(128)
void fin_k(const float* __restrict__ ppos, const float* __restrict__ pneg,
           const float4* __restrict__ colp, float* __restrict__ gred,
           unsigned int* __restrict__ done, float* __restrict__ out)
{
  const int row = blockIdx.x * 128 + threadIdx.x;
  float up = NEGINF, un = POSINF;
  #pragma unroll
  for (int c = 0; c < NCHUNK; ++c){
    up = fmaxf(up, ppos[c * NB + row]);
    un = fminf(un, pneg[c * NB + row]);
  }
  const bool hp = (up > NEGINF);
  const bool hn = (un < POSINF);
  const float pi = colp[row].y;
  float dp = 0.0f, dn = 0.0f;
  // arccosh(1+t) = log1p(t + sqrt(t*(t+2))), t clamped at 1e-7 (matches ref)
  if (hp){ float t = fmaxf(2.0f * up * pi, 1e-7f); dp = log1pf(t + sqrtf(t * (t + 2.0f))); }
  if (hn){ float t = fmaxf(2.0f * un * pi, 1e-7f); dn = log1pf(t + sqrtf(t * (t + 2.0f))); }
  float lsum = (hp && hn) ? fmaxf(dp - dn + 0.5f, 0.0f) : 0.0f;
  float lcnt = (hp && hn) ? 1.0f : 0.0f;
  #pragma unroll
  for (int m = 1; m < 64; m <<= 1){
    lsum += __shfl_xor(lsum, m, 64);
    lcnt += __shfl_xor(lcnt, m, 64);
  }
  __shared__ float2 s_p[2];
  if ((threadIdx.x & 63) == 0) s_p[threadIdx.x >> 6] = make_float2(lsum, lcnt);
  __syncthreads();
  if (threadIdx.x == 0){
    const float bs = s_p[0].x + s_p[1].x;
    const float bc = s_p[0].y + s_p[1].y;
    atomicAdd(&gred[0], bs);
    atomicAdd(&gred[1], bc);
    __threadfence();
    const unsigned int prev = atomicAdd(done, 1u);
    if (prev == 63u){                      // last block: all adds visible
      __threadfence();
      const float s = atomicAdd(&gred[0], 0.0f);   // read via atomic (L2)
      const float c = atomicAdd(&gred[1], 0.0f);
      out[0] = (c > 0.0f) ? (s / c) : 0.0f;
    }
  }
}

extern "C" void kernel_launch(void* const* d_in, const int* in_sizes, int n_in,
                              void* d_out, int out_size, void* d_ws, size_t ws_size,
                              hipStream_t stream)
{
  const float* x  = (const float*)d_in[0];
  const int* lab  = (const int*)d_in[1];
  char* ws = (char*)d_ws;
  u16*    xb   = (u16*)ws;                                        // 2 MB
  float4* colp = (float4*)(ws + (size_t)2*1024*1024);             // 128 KB
  float*  ppos = (float*)(ws + (size_t)2*1024*1024 + 128*1024);   // 512 KB
  float*  pneg = (float*)(ws + (size_t)2*1024*1024 + 128*1024 + 512*1024); // 512 KB
  float*  gred = (float*)(ws + (size_t)2*1024*1024 + 128*1024 + 1024*1024); // 8 B
  unsigned int* done = (unsigned int*)(ws + (size_t)2*1024*1024 + 128*1024
                                          + 1024*1024 + 64);      // 4 B

  hipLaunchKernelGGL(prep_k, dim3(1024), dim3(256), 0, stream, x, lab, xb, colp,
                     gred, done);
  hipLaunchKernelGGL(gram_k, dim3(64, NCHUNK), dim3(256), 0, stream,
                     xb, colp, ppos, pneg);
  hipLaunchKernelGGL(fin_k, dim3(64), dim3(128), 0, stream, ppos, pneg, colp,
                     gred, done, (float*)d_out);
}

// Round 5
// 97.365 us; speedup vs baseline: 1.4935x; 1.0660x over previous
//
#include <hip/hip_runtime.h>
#include <hip/hip_bf16.h>

typedef __attribute__((ext_vector_type(8))) __bf16 bf16x8;
typedef __attribute__((ext_vector_type(4))) float f32x4;
typedef unsigned short u16;

#define NB 8192
#define ND 128
#define NCHUNK 16
#define NEGINF (-__builtin_inff())
#define POSINF (__builtin_inff())

__device__ inline u16 f2b(float f){
  __hip_bfloat16 h = __float2bfloat16(f);
  return *reinterpret_cast<u16*>(&h);
}

// ---- prep: fp32 -> bf16, colp[row] = (sq, p=1/(1-sq), sq*p, lab_bits) ------
// also zeroes the final-reduction cells so fin_k's atomic finish is
// graph-replay-safe (stream order: prep -> gram -> fin every iteration).
extern "C" __global__ __launch_bounds__(256)
void prep_k(const float* __restrict__ x, const int* __restrict__ lab,
            u16* __restrict__ xb, float4* __restrict__ colp,
            float* __restrict__ gred, unsigned int* __restrict__ done)
{
  if (blockIdx.x == 0 && threadIdx.x == 0){
    gred[0] = 0.0f; gred[1] = 0.0f; *done = 0u;
  }
  const int tid = blockIdx.x * 256 + threadIdx.x;
  const int row = tid >> 5;           // 32 threads per row
  const int sub = tid & 31;
  const float4 v = reinterpret_cast<const float4*>(x)[row * 32 + sub];
  float s = v.x*v.x + v.y*v.y + v.z*v.z + v.w*v.w;
  #pragma unroll
  for (int m = 1; m < 32; m <<= 1) s += __shfl_xor(s, m, 32);
  ushort4 o;
  o.x = f2b(v.x); o.y = f2b(v.y); o.z = f2b(v.z); o.w = f2b(v.w);
  reinterpret_cast<ushort4*>(xb)[row * 32 + sub] = o;
  if (sub == 0){
    const float p = 1.0f / (1.0f - s);
    colp[row] = make_float4(s, p, s * p, __int_as_float(lab[row]));
  }
}

// ---- main: bf16 MFMA gram tiles + streaming row max/min --------------------
// grid (64, 16): x = 128-row tile, y = 512-col chunk. 4 waves, each 32 rows.
// K-loop: 8 half-tiles of 64 cols, double-buffered in 2x16KB LDS; stage for
// half-tile s+1 issued before compute(s) (T3-minimum 2-phase).
// PRESSURE DISCIPLINE (rounds 1-2 lesson): (256,4) capped regs at 128 ->
// 20-90 MB scratch. (256,3) + rolled pipeline loop: 84 VGPR, no spill.
// ROUND-4/5: column params (colp panel, 512 x float4 = 8KB) staged into LDS
// once per block -> epilogue reads are ds_read (~50cy) instead of per-use
// global loads (~200cy on the critical path), with ZERO extra register
// live-range across the MFMA block (the round-1 spill trap).
extern "C" __global__ __launch_bounds__(256, 3)
void gram_k(const u16* __restrict__ xb, const float4* __restrict__ colp,
            float* __restrict__ ppos, float* __restrict__ pneg)
{
  __shared__ u16 Bt[2][64 * 128];   // 2 x 16 KB double buffer, 256B/col,
                                    // 16B chunks XOR-swizzled by col&15
  __shared__ float4 cpl[512];       // 8 KB: this block's column params
  const int wid  = threadIdx.x >> 6;
  const int lane = threadIdx.x & 63;
  const int m16  = lane & 15;
  const int quad = lane >> 4;
  const int R0  = blockIdx.x * 128;
  const int C0  = blockIdx.y * 512;
  const int WR0 = R0 + wid * 32;

  // stage the block's 512 colp entries into LDS (lane-linear dest, one-time)
  #pragma unroll
  for (int c = 0; c < 2; ++c){
    const float4* gsrc = colp + C0 + c * 256 + wid * 64 + lane;
    __builtin_amdgcn_global_load_lds(
        (__attribute__((address_space(1))) void*)gsrc,
        (__attribute__((address_space(3))) void*)(cpl + c * 256 + wid * 64),
        16, 0, 0);
  }

  // A fragments in registers: A[m=lane&15][k=quad*8+j]
  bf16x8 afrag[2][4];
  #pragma unroll
  for (int mt = 0; mt < 2; ++mt){
    const u16* arow = xb + (WR0 + mt*16 + m16) * ND;
    #pragma unroll
    for (int ks = 0; ks < 4; ++ks)
      afrag[mt][ks] = *reinterpret_cast<const bf16x8*>(arow + ks*32 + quad*8);
  }

  // per-row (C/D row = quad*4 + r) params
  float sqi[8]; int labi[8];
  #pragma unroll
  for (int mt = 0; mt < 2; ++mt)
    #pragma unroll
    for (int r = 0; r < 4; ++r){
      const float4 cp = colp[WR0 + mt*16 + quad*4 + r];
      sqi[mt*4+r]  = cp.x;
      labi[mt*4+r] = __float_as_int(cp.w);
    }

  float vpos[8], vneg[8];
  #pragma unroll
  for (int i = 0; i < 8; ++i){ vpos[i] = NEGINF; vneg[i] = POSINF; }

  // stage 64 B-rows (16 KB) into buffer b. LDS[col][slot] holds global
  // chunk (slot ^ (col&15)); dest is lane-linear as global_load_lds needs.
  auto stage = [&](int s, int b){
    const int CT0 = C0 + s * 64;
    #pragma unroll
    for (int c = 0; c < 4; ++c){
      const int cc   = wid * 4 + c;        // 16 calls x 1KB = 16KB
      const int brow = cc * 4 + quad;      // stage-local col 0..63
      const int src  = m16 ^ (brow & 15);
      const u16* gsrc = xb + (CT0 + brow) * ND + src * 8;
      __builtin_amdgcn_global_load_lds(
          (__attribute__((address_space(1))) void*)gsrc,
          (__attribute__((address_space(3))) void*)(&Bt[b][cc * 512]), 16, 0, 0);
    }
  };

  auto compute = [&](int s, int b){
    const int CT0 = C0 + s * 64;
    f32x4 acc[2][4];
    #pragma unroll
    for (int mt = 0; mt < 2; ++mt)
      #pragma unroll
      for (int nt = 0; nt < 4; ++nt){
        f32x4 z = {0.f, 0.f, 0.f, 0.f};
        acc[mt][nt] = z;
      }

    #pragma unroll
    for (int ks = 0; ks < 4; ++ks){
      const int t = ks * 4 + quad;                 // 16B chunk index in col
      // per-lane base; nt and buffer terms are compile-time -> fold into
      // the ds_read 16-bit offset immediate
      const u16* bb = &Bt[b][0] + m16 * 128 + ((t ^ m16) * 8);
      #pragma unroll
      for (int nt = 0; nt < 4; ++nt){
        const bf16x8 bfrag = *reinterpret_cast<const bf16x8*>(bb + nt * 2048);
        acc[0][nt] = __builtin_amdgcn_mfma_f32_16x16x32_bf16(afrag[0][ks], bfrag, acc[0][nt], 0, 0, 0);
        acc[1][nt] = __builtin_amdgcn_mfma_f32_16x16x32_bf16(afrag[1][ks], bfrag, acc[1][nt], 0, 0, 0);
      }
    }

    // epilogue: u = (sq_i + sq_j - 2g) * p_j  (no interior clamp; fin clamps)
    // cp read from LDS (staged once per block): ~50cy, no VMEM, no extra
    // register live across the MFMA block.
    #pragma unroll
    for (int nt = 0; nt < 4; ++nt){
      const float4 cp = cpl[s * 64 + nt * 16 + m16];
      const float pj   = cp.y;
      const float spj  = cp.z;
      const int   labj = __float_as_int(cp.w);
      const float n2pj = -2.0f * pj;
      #pragma unroll
      for (int mt = 0; mt < 2; ++mt){
        const bool tilediag = (WR0 + mt*16) == (CT0 + nt*16);
        if (!tilediag){
          #pragma unroll
          for (int r = 0; r < 4; ++r){
            const int idx = mt*4 + r;
            const float u = fmaf(n2pj, acc[mt][nt][r], fmaf(sqi[idx], pj, spj));
            const bool sm = (labi[idx] == labj);
            vpos[idx] = fmaxf(vpos[idx], sm ? u : NEGINF);
            vneg[idx] = fminf(vneg[idx], sm ? POSINF : u);
          }
        } else {
          #pragma unroll
          for (int r = 0; r < 4; ++r){
            const int idx = mt*4 + r;
            const float u = fmaf(n2pj, acc[mt][nt][r], fmaf(sqi[idx], pj, spj));
            const bool sm = (labi[idx] == labj);
            const bool dg = (m16 == quad*4 + r);
            vpos[idx] = fmaxf(vpos[idx], (sm && !dg) ? u : NEGINF);
            vneg[idx] = fminf(vneg[idx], sm ? POSINF : u);
          }
        }
      }
    }
  };

  // pipelined main loop, ROLLED: each iteration handles half-tiles
  // {2ss, 2ss+1} in buffers {0, 1}. Buffer indices are literals; s is
  // runtime so addresses stay incremental (no 8x hoisted address sets).
  stage(0, 0);
  __syncthreads();                       // drains vmcnt(0): tile 0 + cpl ready
  #pragma unroll 1
  for (int ss = 0; ss < 4; ++ss){
    const int s0 = ss * 2;
    stage(s0 + 1, 1);                    // overwrite buf1 (all done reading:
                                         // barrier at end of prev iter)
    compute(s0, 0);
    __syncthreads();                     // buf1 staged; buf0 consumed
    if (ss < 3) stage(s0 + 2, 0);
    compute(s0 + 1, 1);
    if (ss < 3) __syncthreads();         // buf0 staged; buf1 consumed
  }

  // row i lives in the 16 lanes of one quad-group: reduce across them
  #pragma unroll
  for (int i = 0; i < 8; ++i){
    #pragma unroll
    for (int m = 1; m < 16; m <<= 1){
      vpos[i] = fmaxf(vpos[i], __shfl_xor(vpos[i], m, 16));
      vneg[i] = fminf(vneg[i], __shfl_xor(vneg[i], m, 16));
    }
  }
  if (m16 == 0){
    #pragma unroll
    for (int i = 0; i < 8; ++i){
      const int row = WR0 + (i >> 2)*16 + quad*4 + (i & 3);
      ppos[blockIdx.y * NB + row] = vpos[i];
      pneg[blockIdx.y * NB + row] = vneg[i];
    }
  }
}

// ---- finalize (fused): 64 blocks x 128 rows -> atomic finish ---------------
extern "C" __global__ __launch_bounds__(128)
void fin_k(const float* __restrict__ ppos, const float* __restrict__ pneg,
           const float4* __restrict__ colp, float* __restrict__ gred,
           unsigned int* __restrict__ done, float* __restrict__ out)
{
  const int row = blockIdx.x * 128 + threadIdx.x;
  float up = NEGINF, un = POSINF;
  #pragma unroll
  for (int c = 0; c < NCHUNK; ++c){
    up = fmaxf(up, ppos[c * NB + row]);
    un = fminf(un, pneg[c * NB + row]);
  }
  const bool hp = (up > NEGINF);
  const bool hn = (un < POSINF);
  const float pi = colp[row].y;
  float dp = 0.0f, dn = 0.0f;
  // arccosh(1+t) = log1p(t + sqrt(t*(t+2))), t clamped at 1e-7 (matches ref)
  if (hp){ float t = fmaxf(2.0f * up * pi, 1e-7f); dp = log1pf(t + sqrtf(t * (t + 2.0f))); }
  if (hn){ float t = fmaxf(2.0f * un * pi, 1e-7f); dn = log1pf(t + sqrtf(t * (t + 2.0f))); }
  float lsum = (hp && hn) ? fmaxf(dp - dn + 0.5f, 0.0f) : 0.0f;
  float lcnt = (hp && hn) ? 1.0f : 0.0f;
  #pragma unroll
  for (int m = 1; m < 64; m <<= 1){
    lsum += __shfl_xor(lsum, m, 64);
    lcnt += __shfl_xor(lcnt, m, 64);
  }
  __shared__ float2 s_p[2];
  if ((threadIdx.x & 63) == 0) s_p[threadIdx.x >> 6] = make_float2(lsum, lcnt);
  __syncthreads();
  if (threadIdx.x == 0){
    const float bs = s_p[0].x + s_p[1].x;
    const float bc = s_p[0].y + s_p[1].y;
    atomicAdd(&gred[0], bs);
    atomicAdd(&gred[1], bc);
    __threadfence();
    const unsigned int prev = atomicAdd(done, 1u);
    if (prev == 63u){                      // last block: all adds visible
      __threadfence();
      const float s = atomicAdd(&gred[0], 0.0f);   // read via atomic (L2)
      const float c = atomicAdd(&gred[1], 0.0f);
      out[0] = (c > 0.0f) ? (s / c) : 0.0f;
    }
  }
}

extern "C" void kernel_launch(void* const* d_in, const int* in_sizes, int n_in,
                              void* d_out, int out_size, void* d_ws, size_t ws_size,
                              hipStream_t stream)
{
  const float* x  = (const float*)d_in[0];
  const int* lab  = (const int*)d_in[1];
  char* ws = (char*)d_ws;
  u16*    xb   = (u16*)ws;                                        // 2 MB
  float4* colp = (float4*)(ws + (size_t)2*1024*1024);             // 128 KB
  float*  ppos = (float*)(ws + (size_t)2*1024*1024 + 128*1024);   // 512 KB
  float*  pneg = (float*)(ws + (size_t)2*1024*1024 + 128*1024 + 512*1024); // 512 KB
  float*  gred = (float*)(ws + (size_t)2*1024*1024 + 128*1024 + 1024*1024); // 8 B
  unsigned int* done = (unsigned int*)(ws + (size_t)2*1024*1024 + 128*1024
                                          + 1024*1024 + 64);      // 4 B

  hipLaunchKernelGGL(prep_k, dim3(1024), dim3(256), 0, stream, x, lab, xb, colp,
                     gred, done);
  hipLaunchKernelGGL(gram_k, dim3(64, NCHUNK), dim3(256), 0, stream,
                     xb, colp, ppos, pneg);
  hipLaunchKernelGGL(fin_k, dim3(64), dim3(128), 0, stream, ppos, pneg, colp,
                     gred, done, (float*)d_out);
}